// Round 1
// baseline (123.053 us; speedup 1.0000x reference)
//
#include <hip/hip_runtime.h>
#include <stdint.h>

typedef __attribute__((ext_vector_type(8))) __bf16 bf16x8;
typedef __attribute__((ext_vector_type(4))) float f32x4;

#define MFMA_BF16(A, B, C) __builtin_amdgcn_mfma_f32_16x16x32_bf16((A), (B), (C), 0, 0, 0)

namespace {

constexpr int kBatch = 8;
constexpr int kL = 4096;
constexpr int kD = 64;
constexpr int kQB = 64;           // queries per workgroup (4 waves x 16)
constexpr int kKB = 64;           // keys per tile
constexpr int kStride = 72;       // LDS row stride (bf16 elems), padded vs 64
constexpr int kIdxStride = 4160;  // per-batch idx slots (4096 padded to mult of 64)
// log2(e) / D^0.25  (D=64 -> 64^0.25 = 2*sqrt(2))
constexpr float kQScale = 1.4426950408889634f / 2.8284271247461903f;

constexpr size_t kWsPartialOff = 0;      // float[8][8][64] partial column sums
constexpr size_t kWsCountOff = 16384;    // int[8]
constexpr size_t kWsIdxOff = 16448;      // uint16_t[8][4160] compacted indices

// ---------------- kernel 1: per-batch compaction of unmasked token indices ----
__global__ void k_compact(const int* __restrict__ mask, uint16_t* __restrict__ idx,
                          int* __restrict__ counts) {
  const int b = blockIdx.x;
  const int lane = threadIdx.x;  // 64 threads = 1 wave
  const int* mb = mask + b * kL;
  uint16_t* ib = idx + b * kIdxStride;
  int running = 0;
  for (int c = 0; c < kL / 64; ++c) {
    const int k = c * 64 + lane;
    const bool m = (mb[k] != 0);
    const unsigned long long bal = __ballot(m);
    const int pos = running + __popcll(bal & ((1ull << lane) - 1ull));
    if (m) ib[pos] = (uint16_t)k;
    running += __popcll(bal);
  }
  if (lane == 0) counts[b] = running;
  const int padded = (running + 63) & ~63;
  for (int p = running + lane; p < padded; p += 64) ib[p] = 0xFFFFu;
}

// ---------------- kernel 2: partial sums for per-batch column mean ------------
__global__ void k_partial(const float* __restrict__ x, float* __restrict__ partial) {
  const int b = blockIdx.x >> 3;
  const int part = blockIdx.x & 7;
  const int t = threadIdx.x;
  const int d = t & 63;
  const int rs = t >> 6;  // 0..3
  const float* xb = x + (size_t)b * kL * kD;
  float s = 0.0f;
  const int r0 = part * 512 + rs;
  for (int i = 0; i < 128; ++i) s += xb[(size_t)(r0 + i * 4) * kD + d];
  __shared__ float sm[256];
  sm[t] = s;
  __syncthreads();
  if (t < 64) partial[(b * 8 + part) * 64 + t] = sm[t] + sm[t + 64] + sm[t + 128] + sm[t + 192];
}

// ---------------- kernel 3: fill masked rows with the batch mean --------------
__global__ void k_fill(const int* __restrict__ mask, const float* __restrict__ partial,
                       float* __restrict__ out) {
  const int b = blockIdx.x >> 3;
  const int chunk = blockIdx.x & 7;
  const int t = threadIdx.x;
  __shared__ float mean[64];
  if (t < 64) {
    float s = 0.0f;
    for (int p = 0; p < 8; ++p) s += partial[(b * 8 + p) * 64 + t];
    mean[t] = s * (1.0f / (float)kL);
  }
  __syncthreads();
  const int d = t & 63;
  const int rsub = t >> 6;
  for (int i = 0; i < 128; ++i) {
    const int r = chunk * 512 + rsub * 128 + i;
    if (mask[b * kL + r] == 0) out[((size_t)b * kL + r) * kD + d] = mean[d];
  }
}

// ---------------- kernel 4: flash attention over compacted tokens -------------
__global__ __launch_bounds__(256, 2) void k_attn(const float* __restrict__ x,
                                                 const uint16_t* __restrict__ idx,
                                                 const int* __restrict__ counts,
                                                 float* __restrict__ out) {
  const int b = blockIdx.x >> 6;   // 64 q-tiles per batch
  const int qt = blockIdx.x & 63;
  const int count = counts[b];
  if (qt * kQB >= count) return;
  const int NT = (count + kKB - 1) >> 6;

  const float* __restrict__ xb = x + (size_t)b * kL * kD;
  const uint16_t* __restrict__ ib = idx + b * kIdxStride;

  const int tid = threadIdx.x;
  const int wave = tid >> 6;
  const int lane = tid & 63;
  const int lg = lane >> 4;   // lane group 0..3
  const int lr = lane & 15;   // lane row/col 0..15

  __shared__ __align__(16) __bf16 Kh[kKB][kStride];  // bf16 hi of x tile (also V)
  __shared__ __align__(16) __bf16 Kl[kKB][kStride];  // bf16 lo residual

  // ---- Q fragments (Q^T B-frags for S' = K * Q^T): lane holds Q[q=lr][d=kt*32+lg*8+j]
  const int qpos = qt * kQB + wave * 16 + lr;
  const bool qvalid = qpos < count;
  const int q = qvalid ? (int)ib[qpos] : 0;
  bf16x8 qh[2], ql[2];
  {
    const float* qsrc = xb + (size_t)q * kD + lg * 8;
#pragma unroll
    for (int kt = 0; kt < 2; ++kt) {
#pragma unroll
      for (int j = 0; j < 8; ++j) {
        const float f = qsrc[kt * 32 + j] * kQScale;
        const __bf16 hb = (__bf16)f;
        qh[kt][j] = hb;
        ql[kt][j] = (__bf16)(f - (float)hb);
      }
    }
  }

  f32x4 acc[4];  // out^T accumulator: dt tiles; lane holds d = dt*16 + 4*lg + r, col q=lr
#pragma unroll
  for (int i = 0; i < 4; ++i) acc[i] = (f32x4)0.0f;
  float m_run = -1e30f, l_run = 0.0f;

  // staging assignment: thread -> (key row srow, col block sc0)
  const int srow = tid >> 2;
  const int sc0 = (tid & 3) << 4;
  float4 sreg[4];

  // ---- stage tile 0 ----
  {
    const int rowi = (int)ib[srow];
    if (rowi == 0xFFFF) {
      sreg[0] = float4{0, 0, 0, 0}; sreg[1] = float4{0, 0, 0, 0};
      sreg[2] = float4{0, 0, 0, 0}; sreg[3] = float4{0, 0, 0, 0};
    } else {
      const float4* p = (const float4*)(xb + (size_t)rowi * kD + sc0);
      sreg[0] = p[0]; sreg[1] = p[1]; sreg[2] = p[2]; sreg[3] = p[3];
    }
    float v16[16] = {sreg[0].x, sreg[0].y, sreg[0].z, sreg[0].w,
                     sreg[1].x, sreg[1].y, sreg[1].z, sreg[1].w,
                     sreg[2].x, sreg[2].y, sreg[2].z, sreg[2].w,
                     sreg[3].x, sreg[3].y, sreg[3].z, sreg[3].w};
#pragma unroll
    for (int half = 0; half < 2; ++half) {
      bf16x8 hh, ll;
#pragma unroll
      for (int j = 0; j < 8; ++j) {
        const float f = v16[half * 8 + j];
        const __bf16 hb = (__bf16)f;
        hh[j] = hb;
        ll[j] = (__bf16)(f - (float)hb);
      }
      *(bf16x8*)&Kh[srow][sc0 + half * 8] = hh;
      *(bf16x8*)&Kl[srow][sc0 + half * 8] = ll;
    }
  }
  __syncthreads();

  for (int t = 0; t < NT; ++t) {
    const bool havenext = (t + 1 < NT);
    if (havenext) {  // issue next-tile global loads early (hide under compute)
      const int rowi = (int)ib[(t + 1) * kKB + srow];
      if (rowi == 0xFFFF) {
        sreg[0] = float4{0, 0, 0, 0}; sreg[1] = float4{0, 0, 0, 0};
        sreg[2] = float4{0, 0, 0, 0}; sreg[3] = float4{0, 0, 0, 0};
      } else {
        const float4* p = (const float4*)(xb + (size_t)rowi * kD + sc0);
        sreg[0] = p[0]; sreg[1] = p[1]; sreg[2] = p[2]; sreg[3] = p[3];
      }
    }

    // ---- QK: S' = K * Q^T, 4 C-tiles (g: 32-key group, tt: sub-tile) ----
    // A-frag rows permuted: MFMA row rho -> key g*32 + (rho>>2)*8 + tt*4 + (rho&3)
    // => lane's C regs over (tt,r) pack to contiguous k = g*32 + lg*8 + (tt*4+r)
    f32x4 S[2][2];
#pragma unroll
    for (int g = 0; g < 2; ++g) {
#pragma unroll
      for (int tt = 0; tt < 2; ++tt) {
        const int krow = g * 32 + ((lr >> 2) << 3) + tt * 4 + (lr & 3);
        f32x4 s = (f32x4)0.0f;
#pragma unroll
        for (int kt = 0; kt < 2; ++kt) {
          const bf16x8 ah = *(const bf16x8*)&Kh[krow][kt * 32 + lg * 8];
          const bf16x8 al = *(const bf16x8*)&Kl[krow][kt * 32 + lg * 8];
          s = MFMA_BF16(ah, qh[kt], s);
          s = MFMA_BF16(al, qh[kt], s);
          s = MFMA_BF16(ah, ql[kt], s);
        }
        S[g][tt] = s;
      }
    }

    // ---- online softmax over this tile's 64 keys (per column q = lr) ----
    float tm = -1e30f;
#pragma unroll
    for (int g = 0; g < 2; ++g)
#pragma unroll
      for (int tt = 0; tt < 2; ++tt)
#pragma unroll
        for (int r = 0; r < 4; ++r) tm = fmaxf(tm, S[g][tt][r]);
    tm = fmaxf(tm, __shfl_xor(tm, 16));
    tm = fmaxf(tm, __shfl_xor(tm, 32));
    const float m_new = fmaxf(m_run, tm);
    const float corr = __builtin_amdgcn_exp2f(m_run - m_new);

    float p[2][2][4];
#pragma unroll
    for (int g = 0; g < 2; ++g)
#pragma unroll
      for (int tt = 0; tt < 2; ++tt)
#pragma unroll
        for (int r = 0; r < 4; ++r)
          p[g][tt][r] = __builtin_amdgcn_exp2f(S[g][tt][r] - m_new);

    if (t == NT - 1 && (count & 63)) {  // zero padded (sentinel) keys on last tile
      const int valid = count & 63;
#pragma unroll
      for (int g = 0; g < 2; ++g)
#pragma unroll
        for (int tt = 0; tt < 2; ++tt)
#pragma unroll
          for (int r = 0; r < 4; ++r) {
            const int kl2 = g * 32 + lg * 8 + tt * 4 + r;
            if (kl2 >= valid) p[g][tt][r] = 0.0f;
          }
    }

    float lt = 0.0f;
#pragma unroll
    for (int g = 0; g < 2; ++g)
#pragma unroll
      for (int tt = 0; tt < 2; ++tt)
#pragma unroll
        for (int r = 0; r < 4; ++r) lt += p[g][tt][r];
    lt += __shfl_xor(lt, 16);
    lt += __shfl_xor(lt, 32);
    l_run = l_run * corr + lt;
    m_run = m_new;
#pragma unroll
    for (int dt = 0; dt < 4; ++dt) acc[dt] = acc[dt] * corr;

    // pack P' B-frags: frag elem j = tt*4+r holds key g*32 + lg*8 + j  (register-only)
    bf16x8 pf[2];
#pragma unroll
    for (int g = 0; g < 2; ++g)
#pragma unroll
      for (int tt = 0; tt < 2; ++tt)
#pragma unroll
        for (int r = 0; r < 4; ++r) pf[g][tt * 4 + r] = (__bf16)p[g][tt][r];

    // ---- PV: out^T += V^T * P'  (V = Kh, bf16 hi). A-frag: V[k=g*32+lg*8+j][d=dt*16+lr]
#pragma unroll
    for (int g = 0; g < 2; ++g) {
#pragma unroll
      for (int dt = 0; dt < 4; ++dt) {
        bf16x8 vf;
#pragma unroll
        for (int j = 0; j < 8; ++j) vf[j] = Kh[g * 32 + lg * 8 + j][dt * 16 + lr];
        acc[dt] = MFMA_BF16(vf, pf[g], acc[dt]);
      }
    }

    __syncthreads();  // all waves done reading LDS
    if (havenext) {
      float v16[16] = {sreg[0].x, sreg[0].y, sreg[0].z, sreg[0].w,
                       sreg[1].x, sreg[1].y, sreg[1].z, sreg[1].w,
                       sreg[2].x, sreg[2].y, sreg[2].z, sreg[2].w,
                       sreg[3].x, sreg[3].y, sreg[3].z, sreg[3].w};
#pragma unroll
      for (int half = 0; half < 2; ++half) {
        bf16x8 hh, ll;
#pragma unroll
        for (int j = 0; j < 8; ++j) {
          const float f = v16[half * 8 + j];
          const __bf16 hb = (__bf16)f;
          hh[j] = hb;
          ll[j] = (__bf16)(f - (float)hb);
        }
        *(bf16x8*)&Kh[srow][sc0 + half * 8] = hh;
        *(bf16x8*)&Kl[srow][sc0 + half * 8] = ll;
      }
      __syncthreads();  // tile refilled for next iteration
    }
  }

  // ---- epilogue: normalize and store (rows = original token ids) ----
  if (qvalid) {
    const float inv_l = 1.0f / l_run;
    float* op = out + ((size_t)b * kL + q) * kD;
#pragma unroll
    for (int dt = 0; dt < 4; ++dt) {
      const f32x4 r = acc[dt] * inv_l;
      *(f32x4*)(op + dt * 16 + lg * 4) = r;
    }
  }
}

}  // namespace

extern "C" void kernel_launch(void* const* d_in, const int* in_sizes, int n_in,
                              void* d_out, int out_size, void* d_ws, size_t ws_size,
                              hipStream_t stream) {
  const float* x = (const float*)d_in[0];
  const int* mask = (const int*)d_in[1];
  float* out = (float*)d_out;
  float* partial = (float*)((char*)d_ws + kWsPartialOff);
  int* counts = (int*)((char*)d_ws + kWsCountOff);
  uint16_t* idx = (uint16_t*)((char*)d_ws + kWsIdxOff);

  k_compact<<<dim3(kBatch), dim3(64), 0, stream>>>(mask, idx, counts);
  k_partial<<<dim3(kBatch * 8), dim3(256), 0, stream>>>(x, partial);
  k_fill<<<dim3(kBatch * 8), dim3(256), 0, stream>>>(mask, partial, out);
  k_attn<<<dim3(kBatch * (kL / kQB)), dim3(256), 0, stream>>>(x, idx, counts, out);
}